// Round 8
// baseline (815.459 us; speedup 1.0000x reference)
//
#include <hip/hip_runtime.h>
#include <type_traits>

// SOC scan:  SOC[b,t] = SOC_init(b) + sum_{k<=t} g[k],  g[0]=0,
//   g[t] = (ts[t]-ts[t-1]) * f[t-1]
//   f[t] = (c1 + c2*softplus(I*w1e0 + Te*w1e1 + b1e)) * I[t]
//
// R8: R3(8 waves/CU)=132us, R4-R7(16 waves/CU)=61-70us regardless of structure
// -> time scales with RESIDENT WAVES; per-wave load depth saturates ~2-4.
// Lever: 32 waves/CU. Needs <=64 VGPR/wave -> partition rows into 1024-elem
// blocks (x[4]+vals[4] per thread), decoupled aggregate-only lookback through
// d_ws (device-scope atomics, flag|payload packed u64, ws zeroed via
// hipMemsetAsync). p0 folds SOC_init into its aggregate. Predecessor element
// per wave = one direct global load (L2-hot).

static __device__ __forceinline__ float bf2f(unsigned int u) {
    union { unsigned int i; float f; } v;
    v.i = u << 16;
    return v.f;
}
static __device__ __forceinline__ unsigned short f2bf(float f) {
    union { unsigned int i; float f; } v;
    v.f = f;
    unsigned int x = v.i;
    return (unsigned short)((x + 0x7fffu + ((x >> 16) & 1u)) >> 16);  // RNE
}
static __device__ __forceinline__ float sp_fast(float x) {
    return __logf(1.f + __expf(x));   // v_exp_f32 / v_log_f32, |x| << 88
}

struct F4 { float ts, I, Te, U; };
static __device__ __forceinline__ F4 dec(ushort4 x) {
    return {bf2f(x.x), bf2f(x.y), bf2f(x.z), bf2f(x.w)};
}
static __device__ __forceinline__ F4 dec(float4 x) {
    return {x.x, x.y, x.z, x.w};
}

template <bool BF16>
static __device__ __forceinline__ float ld(const void* p, int i) {
    return BF16 ? bf2f(((const unsigned short*)p)[i]) : ((const float*)p)[i];
}

constexpr int BLOCK = 256;
constexpr int PART  = 1024;    // elements per partition-block

// ---------------- partitioned lookback scan ----------------
template <bool BF16>
static __device__ void scan_part(
    const void* __restrict__ Xv, const void* __restrict__ SCv,
    const void* __restrict__ W1i, const void* __restrict__ b1i,
    const void* __restrict__ W2i, const void* __restrict__ b2i,
    const void* __restrict__ W1e, const void* __restrict__ b1e,
    const void* __restrict__ W2e, const void* __restrict__ b2e,
    void* __restrict__ outv, int T, int PPR,
    unsigned long long* __restrict__ slots,
    float* s_wtot, float* s_pref)
{
    using XVec = typename std::conditional<BF16, ushort4, float4>::type;

    const int gb   = blockIdx.x;
    const int b    = gb / PPR;
    const int p    = gb - b * PPR;
    const int tid  = threadIdx.x;
    const int lane = tid & 63;
    const int w    = tid >> 6;
    const int wstart = p * PART + (w << 8);

    const float Q    = ld<BF16>(SCv, b * 4 + 0);
    const float eta0 = ld<BF16>(SCv, b * 4 + 1);
    const float w1e0 = ld<BF16>(W1e, 0);
    const float w1e1 = ld<BF16>(W1e, 1);
    const float vb1e = ld<BF16>(b1e, 0);
    const float coef = eta0 / (3600.f * Q);
    const float c2   = coef * ld<BF16>(W2e, 0);
    const float c1   = coef * (1.f + ld<BF16>(b2e, 0));

    const XVec* Xrow = (const XVec*)Xv + (size_t)b * T;

    // 4 independent chunk loads issued immediately
    XVec x[4];
    #pragma unroll
    for (int j = 0; j < 4; ++j) x[j] = Xrow[wstart + j * 64 + lane];

    // wave-predecessor carry + (p0) SOC_init
    float ts_c, f_c, init = 0.f;
    if (p == 0 && w == 0) {
        const F4 v0 = dec(Xrow[0]);
        ts_c = v0.ts;                      // g[0] = (ts0-ts0)*0 = 0
        f_c  = 0.f;
        const float R  = ld<BF16>(SCv, b * 4 + 2);
        const float S3 = ld<BF16>(SCv, b * 4 + 3);
        const float pre = fmaf(v0.I, ld<BF16>(W1i, 0),
                          fmaf(v0.Te, ld<BF16>(W1i, 1),
                          fmaf(v0.U, ld<BF16>(W1i, 2),
                          fmaf(R, ld<BF16>(W1i, 3), ld<BF16>(b1i, 0)))));
        init = S3 * (1.f + fmaf(sp_fast(pre), ld<BF16>(W2i, 0), ld<BF16>(b2i, 0)));
    } else {
        const F4 vp = dec(Xrow[wstart - 1]);   // L2-hot (neighbor's line)
        f_c  = fmaf(c2, sp_fast(fmaf(vp.I, w1e0, fmaf(vp.Te, w1e1, vb1e))), c1) * vp.I;
        ts_c = vp.ts;
    }

    float vals[4];
    float carry = 0.f;
    #pragma unroll
    for (int j = 0; j < 4; ++j) {
        const F4 v = dec(x[j]);
        const float f = fmaf(c2, sp_fast(fmaf(v.I, w1e0, fmaf(v.Te, w1e1, vb1e))), c1) * v.I;
        float pts = __shfl_up(v.ts, 1, 64);
        float pf  = __shfl_up(f,   1, 64);
        if (lane == 0) { pts = ts_c; pf = f_c; }
        float g = (v.ts - pts) * pf;
        #pragma unroll
        for (int d = 1; d < 64; d <<= 1) {
            const float u = __shfl_up(g, d, 64);
            if (lane >= d) g += u;
        }
        g += carry;
        vals[j] = g;
        carry = __shfl(g, 63, 64);
        ts_c  = __shfl(v.ts, 63, 64);
        f_c   = __shfl(f, 63, 64);
    }
    if (lane == 0) s_wtot[w] = carry;
    __syncthreads();                           // B1: wave totals ready

    if (tid == 0) {
        const float tot = s_wtot[0] + s_wtot[1] + s_wtot[2] + s_wtot[3] + init;
        const unsigned long long pay =
            (1ull << 32) | (unsigned long long)__float_as_uint(tot);
        __hip_atomic_store(&slots[gb], pay, __ATOMIC_RELEASE,
                           __HIP_MEMORY_SCOPE_AGENT);
        // aggregate-only lookback over partitions [rb, gb)
        float pref = init;                     // p==0: just SOC_init
        const int rb = gb - p;
        for (int i = rb; i < gb; ++i) {
            unsigned long long v;
            do {
                v = __hip_atomic_load(&slots[i], __ATOMIC_ACQUIRE,
                                      __HIP_MEMORY_SCOPE_AGENT);
                if (!(v >> 32)) __builtin_amdgcn_s_sleep(1);
            } while (!(v >> 32));
            pref += __uint_as_float((unsigned int)v);
        }
        *s_pref = pref;
    }
    __syncthreads();                           // B2: row prefix ready

    float base = *s_pref;
    #pragma unroll
    for (int ww = 0; ww < 3; ++ww)
        if (ww < w) base += s_wtot[ww];

    if (!BF16) {
        float* op = (float*)outv + (size_t)b * T + wstart + lane;
        #pragma unroll
        for (int j = 0; j < 4; ++j) op[j * 64] = vals[j] + base;
    } else {
        unsigned short* op = (unsigned short*)outv + (size_t)b * T + wstart + lane;
        #pragma unroll
        for (int j = 0; j < 4; ++j) op[j * 64] = f2bf(vals[j] + base);
    }
}

__global__ __launch_bounds__(BLOCK, 8) void socnet_lookback(
    const void* __restrict__ X, const void* __restrict__ SC,
    const void* __restrict__ W1i, const void* __restrict__ b1i,
    const void* __restrict__ W2i, const void* __restrict__ b2i,
    const void* __restrict__ W1e, const void* __restrict__ b1e,
    const void* __restrict__ W2e, const void* __restrict__ b2e,
    void* __restrict__ out, int T, int PPR,
    unsigned long long* __restrict__ slots)
{
    __shared__ float s_wtot[4];
    __shared__ float s_pref;

    // dtype detection from SC (uniform [0.5,1.5]); resolved f32 in round 2
    const unsigned int* scw = (const unsigned int*)SC;
    const float l0 = bf2f(scw[0] & 0xFFFFu), l1 = bf2f(scw[1] & 0xFFFFu);
    const float l2 = bf2f(scw[2] & 0xFFFFu), l3 = bf2f(scw[3] & 0xFFFFu);
    const bool isbf =
        (l0 >= 0.45f && l0 <= 1.55f) && (l1 >= 0.45f && l1 <= 1.55f) &&
        (l2 >= 0.45f && l2 <= 1.55f) && (l3 >= 0.45f && l3 <= 1.55f);

    if (isbf) scan_part<true >(X, SC, W1i, b1i, W2i, b2i, W1e, b1e, W2e, b2e,
                               out, T, PPR, slots, s_wtot, &s_pref);
    else      scan_part<false>(X, SC, W1i, b1i, W2i, b2i, W1e, b1e, W2e, b2e,
                               out, T, PPR, slots, s_wtot, &s_pref);
}

// ---------------- fallback (T % 1024 != 0): serial-carry ----------------
template <bool BF16>
static __device__ void scan_serial(
    const void* __restrict__ Xv, const void* __restrict__ SCv,
    const void* __restrict__ W1i, const void* __restrict__ b1i,
    const void* __restrict__ W2i, const void* __restrict__ b2i,
    const void* __restrict__ W1e, const void* __restrict__ b1e,
    const void* __restrict__ W2e, const void* __restrict__ b2e,
    void* __restrict__ outv, int T,
    float* s_wts, float* s_wf, float* s_wsum, float* s_carr)
{
    using XVec = typename std::conditional<BF16, ushort4, float4>::type;
    const int b = blockIdx.x, tid = threadIdx.x;
    const int lane = tid & 63, wave = tid >> 6;
    const int ntile = (T + BLOCK - 1) / BLOCK;

    const float Q    = ld<BF16>(SCv, b * 4 + 0);
    const float eta0 = ld<BF16>(SCv, b * 4 + 1);
    const float R    = ld<BF16>(SCv, b * 4 + 2);
    const float S3   = ld<BF16>(SCv, b * 4 + 3);
    const float w1e0 = ld<BF16>(W1e, 0);
    const float w1e1 = ld<BF16>(W1e, 1);
    const float vb1e = ld<BF16>(b1e, 0);
    const float coef = eta0 / (3600.f * Q);
    const float c2   = coef * ld<BF16>(W2e, 0);
    const float c1   = coef * (1.f + ld<BF16>(b2e, 0));

    const XVec* Xrow = (const XVec*)Xv + (size_t)b * T;

    for (int tile = 0; tile < ntile; ++tile) {
        const int t = tile * BLOCK + tid;
        const bool act = t < T;
        F4 v = {0.f, 0.f, 0.f, 0.f};
        if (act) v = dec(Xrow[t]);
        const float f = fmaf(c2, sp_fast(fmaf(v.I, w1e0, fmaf(v.Te, w1e1, vb1e))), c1) * v.I;

        float pts = __shfl_up(v.ts, 1, 64);
        float pf  = __shfl_up(f, 1, 64);

        __syncthreads();
        if (lane == 63) { s_wts[wave] = v.ts; s_wf[wave] = f; }
        if (tile == 0 && tid == 0) {
            const float pre = fmaf(v.I, ld<BF16>(W1i, 0),
                              fmaf(v.Te, ld<BF16>(W1i, 1),
                              fmaf(v.U, ld<BF16>(W1i, 2),
                              fmaf(R, ld<BF16>(W1i, 3), ld<BF16>(b1i, 0)))));
            s_carr[0] = S3 * (1.f + fmaf(sp_fast(pre), ld<BF16>(W2i, 0), ld<BF16>(b2i, 0)));
        }
        __syncthreads();
        if (lane == 0) {
            if (wave == 0) { if (tile > 0) { pts = s_carr[1]; pf = s_carr[2]; } }
            else { pts = s_wts[wave - 1]; pf = s_wf[wave - 1]; }
        }
        float g = (t == 0 || !act) ? 0.f : (v.ts - pts) * pf;
        #pragma unroll
        for (int d = 1; d < 64; d <<= 1) {
            const float u = __shfl_up(g, d, 64);
            if (lane >= d) g += u;
        }
        if (lane == 63) s_wsum[wave] = g;
        __syncthreads();
        float soc = s_carr[0];
        #pragma unroll
        for (int w = 0; w < 3; ++w) if (w < wave) soc += s_wsum[w];
        soc += g;
        if (act) {
            if (BF16) ((unsigned short*)outv)[(size_t)b * T + t] = f2bf(soc);
            else      ((float*)outv)[(size_t)b * T + t] = soc;
        }
        __syncthreads();
        if (tid == BLOCK - 1) { s_carr[0] = soc; s_carr[1] = v.ts; s_carr[2] = f; }
    }
}

__global__ __launch_bounds__(BLOCK) void socnet_serial_k(
    const void* __restrict__ X, const void* __restrict__ SC,
    const void* __restrict__ W1i, const void* __restrict__ b1i,
    const void* __restrict__ W2i, const void* __restrict__ b2i,
    const void* __restrict__ W1e, const void* __restrict__ b1e,
    const void* __restrict__ W2e, const void* __restrict__ b2e,
    void* __restrict__ out, int T)
{
    __shared__ float s_wts[4], s_wf[4], s_wsum[4], s_carr[3];
    const unsigned int* scw = (const unsigned int*)SC;
    const float l0 = bf2f(scw[0] & 0xFFFFu), l1 = bf2f(scw[1] & 0xFFFFu);
    const float l2 = bf2f(scw[2] & 0xFFFFu), l3 = bf2f(scw[3] & 0xFFFFu);
    const bool isbf =
        (l0 >= 0.45f && l0 <= 1.55f) && (l1 >= 0.45f && l1 <= 1.55f) &&
        (l2 >= 0.45f && l2 <= 1.55f) && (l3 >= 0.45f && l3 <= 1.55f);
    if (isbf) scan_serial<true >(X, SC, W1i, b1i, W2i, b2i, W1e, b1e, W2e, b2e,
                                 out, T, s_wts, s_wf, s_wsum, s_carr);
    else      scan_serial<false>(X, SC, W1i, b1i, W2i, b2i, W1e, b1e, W2e, b2e,
                                 out, T, s_wts, s_wf, s_wsum, s_carr);
}

extern "C" void kernel_launch(void* const* d_in, const int* in_sizes, int n_in,
                              void* d_out, int out_size, void* d_ws, size_t ws_size,
                              hipStream_t stream) {
    const int B = in_sizes[1] / 4;        // 1024
    const int T = in_sizes[0] / (B * 4);  // 8192

    if (T % PART == 0) {
        const int PPR = T / PART;         // 8
        const int nblk = B * PPR;         // 8192
        hipMemsetAsync(d_ws, 0, (size_t)nblk * sizeof(unsigned long long), stream);
        socnet_lookback<<<dim3(nblk), dim3(BLOCK), 0, stream>>>(
            d_in[0], d_in[1], d_in[2], d_in[3], d_in[4], d_in[5],
            d_in[6], d_in[7], d_in[8], d_in[9], d_out, T, PPR,
            (unsigned long long*)d_ws);
    } else {
        socnet_serial_k<<<dim3(B), dim3(BLOCK), 0, stream>>>(
            d_in[0], d_in[1], d_in[2], d_in[3], d_in[4], d_in[5],
            d_in[6], d_in[7], d_in[8], d_in[9], d_out, T);
    }
}